// Round 8
// baseline (6523.609 us; speedup 1.0000x reference)
//
#include <hip/hip_runtime.h>
#include <math.h>

#define SQH 0.70710678118654752f
typedef unsigned short u16;
using bf16x8 = __attribute__((ext_vector_type(8))) short;
using f32x4  = __attribute__((ext_vector_type(4))) float;

#define HARD_BARRIER() asm volatile("s_barrier" ::: "memory")
#define SCHED_PIN()    __builtin_amdgcn_sched_barrier(0)

__device__ __forceinline__ u16 bfhi(float v) {
    unsigned u = __builtin_bit_cast(unsigned, v);
    return (u16)((u + 0x7FFFu + ((u >> 16) & 1u)) >> 16);
}
__device__ __forceinline__ float bf2f(u16 h) {
    unsigned u = ((unsigned)h) << 16;
    return __builtin_bit_cast(float, u);
}
__device__ __forceinline__ void split2(float v, u16& hi, u16& lo) {
    hi = bfhi(v);
    lo = bfhi(v - bf2f(hi));
}
__device__ __forceinline__ void gl_lds16(const void* g, void* l) {
    __builtin_amdgcn_global_load_lds(
        (const __attribute__((address_space(1))) unsigned*)g,
        (__attribute__((address_space(3))) unsigned*)l, 16, 0, 0);
}

// ---------------------------------------------------------------------------
// upsample: transposed conv, kernel (3,32), lhs_dilation 16 in width.
// ---------------------------------------------------------------------------
__global__ void upsample_k(const float* __restrict__ in, int Tin,
                           const float* __restrict__ w, const float* __restrict__ bb,
                           float* __restrict__ out, int Tout)
{
    int idx = blockIdx.x * 256 + threadIdx.x;
    if (idx >= 80 * Tout) return;
    int oh = idx / Tout, ow = idx - oh * Tout;
    float acc = bb[0];
    int kw0 = (23 - (ow & 15)) & 15;
#pragma unroll
    for (int kh = 0; kh < 3; ++kh) {
        int ih = oh - 1 + kh;
        if (ih < 0 || ih >= 80) continue;
#pragma unroll
        for (int m = 0; m < 2; ++m) {
            int kw = kw0 + 16 * m;
            int j = ow - 23 + kw;
            if (j < 0) continue;
            int src = j >> 4;
            if (src < Tin)
                acc = fmaf(w[(2 - kh) * 32 + (31 - kw)], in[ih * Tin + src], acc);
        }
    }
    out[idx] = acc > 0.f ? acc : 0.4f * acc;
}

__global__ void squeeze_x_k(const float* __restrict__ x, float* __restrict__ o)
{
    int idx = blockIdx.x * 256 + threadIdx.x;
    int i = idx >> 11, j = idx & 2047;
    o[idx] = x[(j << 4) + i];
}

__global__ void zero2_k(float* __restrict__ logdet, float* __restrict__ zbuf)
{
    if (threadIdx.x == 0) logdet[0] = 0.f;
    zbuf[threadIdx.x] = 0.f;
}

// c2T[r][t][96cc] hi/lo bf16, zero-padded 80->96
__global__ void c2t_k(const float* __restrict__ cup, u16* __restrict__ THi, u16* __restrict__ TLo)
{
    int idx = blockIdx.x * 256 + threadIdx.x;   // 16*2048*96
    int cc = idx % 96; int rt = idx / 96; int t = rt & 2047; int rr = rt >> 11;
    float v = (cc < 80) ? cup[(size_t)cc * 32768 + t * 16 + rr] : 0.f;
    u16 hi, lo; split2(v, hi, lo);
    THi[idx] = hi; TLo[idx] = lo;
}

// per-flow conv weights -> Wc[l][tap][s][ic] hi/lo (s = gate-permuted oc)
__global__ void wc_cvt_k(const float* __restrict__ fgw, u16* __restrict__ WHi, u16* __restrict__ WLo)
{
    int idx = blockIdx.x * 256 + threadIdx.x;   // 8*256*128
    int ic = idx & 127, s = (idx >> 7) & 255, l = idx >> 15;
    int oc = ((s >> 7) << 6) + (((s >> 6) & 1) << 5) + (s & 31) + (((s >> 5) & 1) << 7);
    const float* src = fgw + ((size_t)(l * 256 + oc) * 128 + ic) * 9;
#pragma unroll
    for (int tap = 0; tap < 9; ++tap) {
        u16 hi, lo; split2(src[tap], hi, lo);
        size_t o = ((size_t)(l * 9 + tap) * 256 + s) * 128 + ic;
        WHi[o] = hi; WLo[o] = lo;
    }
}

// cond weights -> Wd[fl][s][96] hi/lo (all 64 layers)
__global__ void wd_cvt_k(const float* __restrict__ fgcw, u16* __restrict__ WHi, u16* __restrict__ WLo)
{
    int idx = blockIdx.x * 256 + threadIdx.x;   // 64*256*96
    int cc = idx % 96; int rest = idx / 96; int s = rest & 255; int fl = rest >> 8;
    int oc = ((s >> 7) << 6) + (((s >> 6) & 1) << 5) + (s & 31) + (((s >> 5) & 1) << 7);
    float v = (cc < 80) ? fgcw[((size_t)fl * 256 + oc) * 80 + cc] : 0.f;
    u16 hi, lo; split2(v, hi, lo);
    WHi[idx] = hi; WLo[idx] = lo;
}

__global__ void wrs_cvt_k(const float* __restrict__ rsw, u16* __restrict__ WHi, u16* __restrict__ WLo)
{
    int idx = blockIdx.x * 256 + threadIdx.x;   // 64*16384
    u16 hi, lo; split2(rsw[idx], hi, lo);
    WHi[idx] = hi; WLo[idx] = lo;
}

// front 1x1: h fp32 [ch][rt] + hT hi/lo [rt][128ch]; zeroes lsacc
__global__ void front_k(const float* __restrict__ X, float* __restrict__ h,
                        u16* __restrict__ hTHi, u16* __restrict__ hTLo,
                        const float* __restrict__ fw, const float* __restrict__ fb,
                        float* __restrict__ lsacc)
{
    int bid = blockIdx.x, tid = threadIdx.x;
    if (bid < 960) {
        int rt = bid * 32 + (tid >> 3);
        int ch0 = (tid & 7) << 4;
        float xv = X[rt];
        unsigned hs[8], ls[8];
#pragma unroll
        for (int k = 0; k < 16; k += 2) {
            float v0 = fmaf(fw[ch0 + k], xv, fb[ch0 + k]);
            float v1 = fmaf(fw[ch0 + k + 1], xv, fb[ch0 + k + 1]);
            h[(size_t)(ch0 + k) * 30720 + rt] = v0;
            h[(size_t)(ch0 + k + 1) * 30720 + rt] = v1;
            u16 h0, l0, h1, l1; split2(v0, h0, l0); split2(v1, h1, l1);
            hs[k >> 1] = (unsigned)h0 | ((unsigned)h1 << 16);
            ls[k >> 1] = (unsigned)l0 | ((unsigned)l1 << 16);
        }
        uint4* dh4 = (uint4*)(hTHi + (size_t)rt * 128 + ch0);
        dh4[0] = make_uint4(hs[0], hs[1], hs[2], hs[3]);
        dh4[1] = make_uint4(hs[4], hs[5], hs[6], hs[7]);
        uint4* dl4 = (uint4*)(hTLo + (size_t)rt * 128 + ch0);
        dl4[0] = make_uint4(ls[0], ls[1], ls[2], ls[3]);
        dl4[1] = make_uint4(ls[4], ls[5], ls[6], ls[7]);
    } else {
        int i = (bid - 960) * 256 + tid;    // 60 blocks * 256 = 15360 float4
        ((float4*)lsacc)[i] = make_float4(0.f, 0.f, 0.f, 0.f);
    }
}

// ---------------------------------------------------------------------------
// conv + cond + gate via split-bf16 MFMA, 2-phase double-buffered pipeline.
// LDS: 2 x 32KB buffers (Ahi|Alo|Bhi|Blo slabs of 8KB), chunk-major layout
// addr(row,kc) = (row>>4)*1024 + kc*256 + (row&15)*16 via lane-source permute.
// Main loop: STAGE(ci+1 -> buf^1); vmcnt(8); barrier; ds_read+MFMA; barrier.
// Barriers carry "memory" clobbers atomically; sched_barrier(0) pins the
// waitcnt->barrier->compute ordering against scheduler hoisting (rule #18).
// ---------------------------------------------------------------------------
__global__ __launch_bounds__(256)
void conv_gate_mfma(const u16* __restrict__ hTHi, const u16* __restrict__ hTLo,
                    const u16* __restrict__ c2THi, const u16* __restrict__ c2TLo,
                    const u16* __restrict__ WcHi, const u16* __restrict__ WcLo,
                    const u16* __restrict__ WdHi, const u16* __restrict__ WdLo,
                    const float* __restrict__ fgb, const float* __restrict__ fgcb,
                    u16* __restrict__ oTHi, u16* __restrict__ oTLo,
                    const float* __restrict__ zbuf,
                    int dh, int dw, int rev)
{
    __shared__ char lds[65536];   // 2 x {Ahi 0 | Alo 8K | Bhi 16K | Blo 24K}
    const int tid = threadIdx.x;
    const int lane = tid & 63, w = tid >> 6;
    const int wm = w & 1, wn = w >> 1;
    const int t0 = blockIdx.x << 7;
    const int r  = blockIdx.y;
    const int ocb = blockIdx.z;
    const int si = lane & 15;        // row-within-16 (staging / frag)
    const int sc = lane >> 4;        // k-chunk 0..3

    const int khmin = (r >= 2 * dh) ? 0 : ((r >= dh) ? 1 : 2);
    const int nconv = (3 - khmin) * 12;
    const int n = nconv + 3;
    const int rrow = rev ? (14 - r) : (r + 1);

    f32x4 acc[4][4];
#pragma unroll
    for (int fm = 0; fm < 4; ++fm) {
        int ocx = (ocb << 6) + (wm << 5) + ((fm & 1) << 4) + (sc << 2) + ((fm >> 1) << 7);
        f32x4 b;
#pragma unroll
        for (int rg = 0; rg < 4; ++rg) b[rg] = fgb[ocx + rg] + fgcb[ocx + rg];
#pragma unroll
        for (int fn = 0; fn < 4; ++fn) acc[fm][fn] = b;
    }

    auto STAGE = [&](int ci, char* bufb) {
        const u16 *aH, *aL, *bH, *bL;
        int aStr, bStr, k0, shift, bounded;
        if (ci < nconv) {
            int tap = khmin * 3 + (ci >> 2);
            int kh = tap / 3, kw = tap - kh * 3;
            shift = (kw - 1) * dw;
            int rr = r - (2 - kh) * dh;
            size_t aOff = ((size_t)tap * 256 + (size_t)ocb * 128) * 128;
            aH = WcHi + aOff; aL = WcLo + aOff;
            size_t bOff = (size_t)rr * 262144;
            bH = hTHi + bOff; bL = hTLo + bOff;
            aStr = 128; bStr = 128; k0 = (ci & 3) << 5; bounded = 1;
        } else {
            int q = ci - nconv;
            size_t aOff = (size_t)ocb * 12288;
            aH = WdHi + aOff; aL = WdLo + aOff;
            size_t bOff = (size_t)rrow * 196608;
            bH = c2THi + bOff; bL = c2TLo + bOff;
            aStr = 96; bStr = 96; k0 = q << 5; shift = 0; bounded = 0;
        }
#pragma unroll
        for (int e = 0; e < 2; ++e) {
            int rowA = (w << 5) + (e << 4) + si;
            int lb = (w << 11) + (e << 10);
            gl_lds16(aH + (size_t)rowA * aStr + k0 + sc * 8, bufb + lb);
            gl_lds16(aL + (size_t)rowA * aStr + k0 + sc * 8, bufb + 8192 + lb);
            int cc = t0 + rowA + shift;
            const u16* sh = bH + (size_t)cc * bStr + k0 + sc * 8;
            const u16* sl = bL + (size_t)cc * bStr + k0 + sc * 8;
            if (bounded && (unsigned)cc >= 2048u) { sh = (const u16*)zbuf; sl = (const u16*)zbuf; }
            gl_lds16(sh, bufb + 16384 + lb);
            gl_lds16(sl, bufb + 24576 + lb);
        }
    };

    auto COMPUTE = [&](const char* bufb) {
        bf16x8 aF[4][2];
#pragma unroll
        for (int fm = 0; fm < 4; ++fm) {
            int off = (((wm << 2) + fm) << 10) + (sc << 8) + (si << 4);
            aF[fm][0] = *(const bf16x8*)(bufb + off);
            aF[fm][1] = *(const bf16x8*)(bufb + 8192 + off);
        }
        __builtin_amdgcn_s_setprio(1);
#pragma unroll
        for (int fn = 0; fn < 4; ++fn) {
            int off = (((wn << 2) + fn) << 10) + (sc << 8) + (si << 4);
            bf16x8 bH8 = *(const bf16x8*)(bufb + 16384 + off);
            bf16x8 bL8 = *(const bf16x8*)(bufb + 24576 + off);
#pragma unroll
            for (int fm = 0; fm < 4; ++fm) {
                acc[fm][fn] = __builtin_amdgcn_mfma_f32_16x16x32_bf16(aF[fm][0], bH8, acc[fm][fn], 0, 0, 0);
                acc[fm][fn] = __builtin_amdgcn_mfma_f32_16x16x32_bf16(aF[fm][1], bH8, acc[fm][fn], 0, 0, 0);
                acc[fm][fn] = __builtin_amdgcn_mfma_f32_16x16x32_bf16(aF[fm][0], bL8, acc[fm][fn], 0, 0, 0);
            }
        }
        __builtin_amdgcn_s_setprio(0);
    };

    STAGE(0, lds);
    int cur = 0;
    for (int ci = 0; ci < n - 1; ++ci) {
        STAGE(ci + 1, lds + ((cur ^ 1) << 15));
        asm volatile("s_waitcnt vmcnt(8)" ::: "memory");
        SCHED_PIN();
        HARD_BARRIER();
        SCHED_PIN();
        COMPUTE(lds + (cur << 15));
        SCHED_PIN();
        HARD_BARRIER();
        SCHED_PIN();
        cur ^= 1;
    }
    asm volatile("s_waitcnt vmcnt(0)" ::: "memory");
    SCHED_PIN();
    HARD_BARRIER();
    SCHED_PIN();
    COMPUTE(lds + (cur << 15));

    // gated activation (frag q = tanh rows, q+2 = sigmoid of same oc pairs)
    float ov[2][4][4];
#pragma unroll
    for (int q = 0; q < 2; ++q)
#pragma unroll
        for (int fn = 0; fn < 4; ++fn)
#pragma unroll
            for (int rg = 0; rg < 4; ++rg) {
                float tv = acc[q][fn][rg], sv = acc[q + 2][fn][rg];
                ov[q][fn][rg] = tanhf(tv) * (1.f / (1.f + expf(-sv)));
            }

    // LDS-transposed coalesced store of oT hi/lo [r][t][p]
#pragma unroll
    for (int pl = 0; pl < 2; ++pl) {
        __syncthreads();
#pragma unroll
        for (int q = 0; q < 2; ++q)
#pragma unroll
            for (int fn = 0; fn < 4; ++fn) {
                int tl = (wn << 6) + (fn << 4) + si;
                int p0 = (wm << 5) + (q << 4) + (sc << 2);
                u16 s[4];
#pragma unroll
                for (int rg = 0; rg < 4; ++rg) {
                    float v = ov[q][fn][rg];
                    u16 hi = bfhi(v);
                    s[rg] = pl ? bfhi(v - bf2f(hi)) : hi;
                }
                uint2 val;
                val.x = (unsigned)s[0] | ((unsigned)s[1] << 16);
                val.y = (unsigned)s[2] | ((unsigned)s[3] << 16);
                *(uint2*)(lds + tl * 128 + ((p0 ^ ((tl & 7) << 3)) << 1)) = val;
            }
        __syncthreads();
        u16* dst = pl ? oTLo : oTHi;
#pragma unroll
        for (int e = 0; e < 4; ++e) {
            int tl = (tid >> 3) + (e << 5);
            int pg = tid & 7;
            uint4 v = *(const uint4*)(lds + tl * 128 + ((pg ^ (tl & 7)) << 4));
            *(uint4*)(dst + ((size_t)r * 2048 + t0 + tl) * 128 + (ocb << 6) + (pg << 3)) = v;
        }
    }
}

// ---------------------------------------------------------------------------
// h = (h + rs_w @ oact + b)*SQH  via split-bf16 MFMA; 2-phase pipelined.
// ---------------------------------------------------------------------------
__global__ __launch_bounds__(256)
void rs_mfma(float* __restrict__ h, const u16* __restrict__ oTHi, const u16* __restrict__ oTLo,
             const u16* __restrict__ WHi, const u16* __restrict__ WLo,
             const float* __restrict__ rsb,
             u16* __restrict__ hTHi, u16* __restrict__ hTLo)
{
    __shared__ char lds[49152];   // 2 x {Ahi 0 | Alo 8K | Bhi 16K | Blo 20K}
    const int tid = threadIdx.x;
    const int lane = tid & 63, w = tid >> 6;
    const int wm = w & 1, wn = w >> 1;
    const int t0 = blockIdx.x << 6;
    const int r = blockIdx.y;
    const int si = lane & 15, sc = lane >> 4;

    f32x4 acc[4][2];
#pragma unroll
    for (int fm = 0; fm < 4; ++fm)
#pragma unroll
        for (int fn = 0; fn < 2; ++fn)
#pragma unroll
            for (int rg = 0; rg < 4; ++rg) acc[fm][fn][rg] = 0.f;

    auto STAGE = [&](int icq, char* bufb) {
        int k0 = icq << 5;
#pragma unroll
        for (int e = 0; e < 2; ++e) {
            int rowA = (w << 5) + (e << 4) + si;
            int lb = (w << 11) + (e << 10);
            gl_lds16(WHi + (size_t)rowA * 128 + k0 + sc * 8, bufb + lb);
            gl_lds16(WLo + (size_t)rowA * 128 + k0 + sc * 8, bufb + 8192 + lb);
        }
        int tt = (w << 4) + si;
        int lb = (w << 10);
        gl_lds16(oTHi + ((size_t)r * 2048 + t0 + tt) * 128 + k0 + sc * 8, bufb + 16384 + lb);
        gl_lds16(oTLo + ((size_t)r * 2048 + t0 + tt) * 128 + k0 + sc * 8, bufb + 20480 + lb);
    };

    auto COMPUTE = [&](const char* bufb) {
        bf16x8 aF[4][2];
#pragma unroll
        for (int fm = 0; fm < 4; ++fm) {
            int off = (((wm << 2) + fm) << 10) + (sc << 8) + (si << 4);
            aF[fm][0] = *(const bf16x8*)(bufb + off);
            aF[fm][1] = *(const bf16x8*)(bufb + 8192 + off);
        }
        __builtin_amdgcn_s_setprio(1);
#pragma unroll
        for (int fn = 0; fn < 2; ++fn) {
            int off = (((wn << 1) + fn) << 10) + (sc << 8) + (si << 4);
            bf16x8 bH8 = *(const bf16x8*)(bufb + 16384 + off);
            bf16x8 bL8 = *(const bf16x8*)(bufb + 20480 + off);
#pragma unroll
            for (int fm = 0; fm < 4; ++fm) {
                acc[fm][fn] = __builtin_amdgcn_mfma_f32_16x16x32_bf16(aF[fm][0], bH8, acc[fm][fn], 0, 0, 0);
                acc[fm][fn] = __builtin_amdgcn_mfma_f32_16x16x32_bf16(aF[fm][1], bH8, acc[fm][fn], 0, 0, 0);
                acc[fm][fn] = __builtin_amdgcn_mfma_f32_16x16x32_bf16(aF[fm][0], bL8, acc[fm][fn], 0, 0, 0);
            }
        }
        __builtin_amdgcn_s_setprio(0);
    };

    STAGE(0, lds);
    int cur = 0;
    for (int icq = 0; icq < 3; ++icq) {
        STAGE(icq + 1, lds + (cur ^ 1) * 24576);
        asm volatile("s_waitcnt vmcnt(6)" ::: "memory");
        SCHED_PIN();
        HARD_BARRIER();
        SCHED_PIN();
        COMPUTE(lds + cur * 24576);
        SCHED_PIN();
        HARD_BARRIER();
        SCHED_PIN();
        cur ^= 1;
    }
    asm volatile("s_waitcnt vmcnt(0)" ::: "memory");
    SCHED_PIN();
    HARD_BARRIER();
    SCHED_PIN();
    COMPUTE(lds + cur * 24576);

    float hv[4][2][4];
#pragma unroll
    for (int fm = 0; fm < 4; ++fm)
#pragma unroll
        for (int fn = 0; fn < 2; ++fn) {
            int t = t0 + (wn << 5) + (fn << 4) + si;
#pragma unroll
            for (int rg = 0; rg < 4; ++rg) {
                int ch = (wm << 6) + (fm << 4) + (sc << 2) + rg;
                size_t off = (size_t)ch * 30720 + (size_t)r * 2048 + t;
                float nv = (h[off] + acc[fm][fn][rg] + rsb[ch]) * SQH;
                h[off] = nv;
                hv[fm][fn][rg] = nv;
            }
        }

#pragma unroll
    for (int pl = 0; pl < 2; ++pl) {
        __syncthreads();
#pragma unroll
        for (int fm = 0; fm < 4; ++fm)
#pragma unroll
            for (int fn = 0; fn < 2; ++fn) {
                int tl = (wn << 5) + (fn << 4) + si;
                int ch0 = (wm << 6) + (fm << 4) + (sc << 2);
                u16 s[4];
#pragma unroll
                for (int rg = 0; rg < 4; ++rg) {
                    float v = hv[fm][fn][rg];
                    u16 hi = bfhi(v);
                    s[rg] = pl ? bfhi(v - bf2f(hi)) : hi;
                }
                uint2 val;
                val.x = (unsigned)s[0] | ((unsigned)s[1] << 16);
                val.y = (unsigned)s[2] | ((unsigned)s[3] << 16);
                *(uint2*)(lds + tl * 256 + ((ch0 ^ ((tl & 7) << 3)) << 1)) = val;
            }
        __syncthreads();
        u16* dst = pl ? hTLo : hTHi;
#pragma unroll
        for (int e = 0; e < 4; ++e) {
            int tl = (tid >> 4) + (e << 4);
            int chg = tid & 15;
            uint4 v = *(const uint4*)(lds + tl * 256 + ((chg ^ (tl & 7)) << 4));
            *(uint4*)(dst + ((size_t)r * 2048 + t0 + tl) * 128 + (chg << 3)) = v;
        }
    }
}

// lsacc += proj_w . (oT hi+lo); 4 lanes per (r,t), shfl-reduced
__global__ void lsadd_k(float* __restrict__ lsacc, const u16* __restrict__ oTHi,
                        const u16* __restrict__ oTLo, const float* __restrict__ pw)
{
    int gid = blockIdx.x * 256 + threadIdx.x;   // 122880
    int idx = gid >> 2, part = gid & 3;
    const uint4* ph = (const uint4*)(oTHi + (size_t)idx * 128 + part * 32);
    const uint4* pl = (const uint4*)(oTLo + (size_t)idx * 128 + part * 32);
    float a0 = 0.f, a1 = 0.f;
#pragma unroll
    for (int g = 0; g < 4; ++g) {
        uint4 vh = ph[g], vl = pl[g];
        const unsigned* uh = &vh.x; const unsigned* ul = &vl.x;
#pragma unroll
        for (int j = 0; j < 4; ++j) {
            int ic = part * 32 + g * 8 + j * 2;
            float v0 = bf2f((u16)(uh[j] & 0xffffu)) + bf2f((u16)(ul[j] & 0xffffu));
            float v1 = bf2f((u16)(uh[j] >> 16)) + bf2f((u16)(ul[j] >> 16));
            a0 = fmaf(pw[ic], v0, a0);       a0 = fmaf(pw[ic + 1], v1, a0);
            a1 = fmaf(pw[128 + ic], v0, a1); a1 = fmaf(pw[128 + ic + 1], v1, a1);
        }
    }
    a0 += __shfl_xor(a0, 1); a0 += __shfl_xor(a0, 2);
    a1 += __shfl_xor(a1, 1); a1 += __shfl_xor(a1, 2);
    if (part == 0) {
        lsacc[idx] += a0;
        lsacc[30720 + idx] += a1;
    }
}

// affine coupling + folded reversal + logdet
__global__ void update_k(const float* __restrict__ Xc, float* __restrict__ Xn,
                         const float* __restrict__ lsacc, const float* __restrict__ pb,
                         const float* __restrict__ psc, float* __restrict__ logdet)
{
    int idx = blockIdx.x * 256 + threadIdx.x;   // 30720
    int rr = idx >> 11, t = idx & 2047;
    float e0 = expf(3.f * psc[0]), e1 = expf(3.f * psc[1]);
    float ls0 = (lsacc[idx] + pb[0]) * e0;
    float ls1 = (lsacc[30720 + idx] + pb[1]) * e1;
    float xn = fmaf(Xc[idx + 2048], expf(ls0), ls1);
    Xn[(14 - rr) * 2048 + t] = xn;
    if (idx < 2048) Xn[15 * 2048 + idx] = Xc[idx];
    float s = ls0;
#pragma unroll
    for (int o = 32; o > 0; o >>= 1) s += __shfl_down(s, o);
    if ((threadIdx.x & 63) == 0) atomicAdd(logdet, s);
}

// ---------------------------------------------------------------------------
extern "C" void kernel_launch(void* const* d_in, const int* in_sizes, int n_in,
                              void* d_out, int out_size, void* d_ws, size_t ws_size,
                              hipStream_t stream)
{
    const float* x       = (const float*)d_in[0];
    const float* c       = (const float*)d_in[1];
    const float* front_w = (const float*)d_in[2];
    const float* front_b = (const float*)d_in[3];
    const float* fg_w    = (const float*)d_in[4];
    const float* fg_b    = (const float*)d_in[5];
    const float* fgc_w   = (const float*)d_in[6];
    const float* fgc_b   = (const float*)d_in[7];
    const float* rs_w    = (const float*)d_in[8];
    const float* rs_b    = (const float*)d_in[9];
    const float* proj_w  = (const float*)d_in[10];
    const float* proj_b  = (const float*)d_in[11];
    const float* proj_s  = (const float*)d_in[12];
    const float* up_w1   = (const float*)d_in[13];
    const float* up_b1   = (const float*)d_in[14];
    const float* up_w2   = (const float*)d_in[15];
    const float* up_b2   = (const float*)d_in[16];
    float* out = (float*)d_out;

    float* base = (float*)d_ws;
    float* c1   = base;                  // 163840
    float* cup  = c1 + 163840;           // 2621440
    float* lsac = cup + 2621440;         // 61440
    float* outA = lsac + 61440;          // 32768
    float* outB = outA + 32768;          // 32768
    float* zbuf = outB + 32768;          // 64
    float* h    = zbuf + 64;             // 3932160
    u16* u = (u16*)(h + 3932160);
    u16* hTHi = u;  u += 3932160;
    u16* hTLo = u;  u += 3932160;
    u16* oTHi = u;  u += 3932160;
    u16* oTLo = u;  u += 3932160;
    u16* c2THi = u; u += 3145728;
    u16* c2TLo = u; u += 3145728;
    u16* WdHi = u;  u += 1572864;
    u16* WdLo = u;  u += 1572864;
    u16* WrsHi = u; u += 1048576;
    u16* WrsLo = u; u += 1048576;
    u16* WcHi = u;  u += 2359296;
    u16* WcLo = u;  u += 2359296;

    upsample_k<<<640, 256, 0, stream>>>(c, 128, up_w1, up_b1, c1, 2048);
    upsample_k<<<10240, 256, 0, stream>>>(c1, 2048, up_w2, up_b2, cup, 32768);
    c2t_k<<<12288, 256, 0, stream>>>(cup, c2THi, c2TLo);
    squeeze_x_k<<<128, 256, 0, stream>>>(x, outA);
    zero2_k<<<1, 64, 0, stream>>>(out + 32768, zbuf);
    wd_cvt_k<<<6144, 256, 0, stream>>>(fgc_w, WdHi, WdLo);
    wrs_cvt_k<<<4096, 256, 0, stream>>>(rs_w, WrsHi, WrsLo);

    float* Xc = outA;
    float* Xn = outB;
    for (int i = 0; i < 8; ++i) {
        int rev = i & 1;
        wc_cvt_k<<<1024, 256, 0, stream>>>(fg_w + (size_t)i * 2359296, WcHi, WcLo);
        front_k<<<1020, 256, 0, stream>>>(Xc, h, hTHi, hTLo,
                                          front_w + i * 128, front_b + i * 128, lsac);
        for (int l = 0; l < 8; ++l) {
            int fl = i * 8 + l;
            int dh = 1 << (l % 3), dw = 1 << l;
            conv_gate_mfma<<<dim3(16, 15, 2), 256, 0, stream>>>(
                hTHi, hTLo, c2THi, c2TLo,
                WcHi + (size_t)l * 9 * 256 * 128, WcLo + (size_t)l * 9 * 256 * 128,
                WdHi + (size_t)fl * 256 * 96, WdLo + (size_t)fl * 256 * 96,
                fg_b + fl * 256, fgc_b + fl * 256,
                oTHi, oTLo, zbuf, dh, dw, rev);
            lsadd_k<<<480, 256, 0, stream>>>(lsac, oTHi, oTLo, proj_w + i * 256);
            if (l < 7)
                rs_mfma<<<dim3(32, 15), 256, 0, stream>>>(h, oTHi, oTLo,
                    WrsHi + (size_t)fl * 16384, WrsLo + (size_t)fl * 16384,
                    rs_b + fl * 128, hTHi, hTLo);
        }
        float* dst = (i == 7) ? out : Xn;
        update_k<<<120, 256, 0, stream>>>(Xc, dst, lsac, proj_b + i * 2,
                                          proj_s + i * 2, out + 32768);
        float* tmp = Xc; Xc = Xn; Xn = tmp;
    }
}